// Round 5
// baseline (314.587 us; speedup 1.0000x reference)
//
#include <hip/hip_runtime.h>
#include <hip/hip_bf16.h>
#include <math.h>

// B=2, T=2048, D=1024, H=16, hd=64, ALPHA=1 (decay = -(i-j))
// Pipeline: fused cast f32->bf16 -> fused QKV NT-GEMM (V transposed) -> flash attn -> out GEMM (f32)

typedef __bf16 bf16_t;
typedef bf16_t bf16x8 __attribute__((ext_vector_type(8)));
typedef bf16_t bf16x4 __attribute__((ext_vector_type(4)));
typedef float  floatx4 __attribute__((ext_vector_type(4)));

#define LOG2E 1.44269504088896f

#if __has_builtin(__builtin_amdgcn_exp2f)
#define EXP2(x) __builtin_amdgcn_exp2f(x)
#else
#define EXP2(x) exp2f(x)
#endif

__device__ __forceinline__ void async16(const bf16_t* g, bf16_t* l) {
  __builtin_amdgcn_global_load_lds(
      (const __attribute__((address_space(1))) unsigned int*)g,
      (__attribute__((address_space(3))) unsigned int*)l, 16, 0, 0);
}

// pack two f32 into bf16x2 by truncation (1 v_perm_b32); P in [0,~20] -> rel err <= 2^-8
__device__ __forceinline__ unsigned pack_bf16_trunc(float lo, float hi) {
  return __builtin_amdgcn_perm(__builtin_bit_cast(unsigned, hi),
                               __builtin_bit_cast(unsigned, lo), 0x07060302u);
}

// ---------------- fused cast kernel ----------------
__global__ void castall(const float* __restrict__ x,
                        const float* __restrict__ wq, const float* __restrict__ wk,
                        const float* __restrict__ wv, const float* __restrict__ wo,
                        bf16_t* __restrict__ xb, bf16_t* __restrict__ wdst) {
  int i = blockIdx.x * blockDim.x + threadIdx.x;  // 0 .. 2097151
  const float* src;
  bf16_t* dst;
  if (i < 1048576) {
    src = x + (size_t)i * 4;
    dst = xb + (size_t)i * 4;
  } else {
    int i2 = i - 1048576;
    int wsel = i2 >> 18;
    int off = i2 & 262143;
    const float* wsrc = (wsel == 0) ? wq : (wsel == 1) ? wk : (wsel == 2) ? wv : wo;
    src = wsrc + (size_t)off * 4;
    dst = wdst + (size_t)i2 * 4;
  }
  const float4 f = *(const float4*)src;
  bf16x4 o;
  o[0] = (bf16_t)f.x; o[1] = (bf16_t)f.y; o[2] = (bf16_t)f.z; o[3] = (bf16_t)f.w;
  *(bf16x4*)dst = o;
}

// ---------------- NT GEMM: C[m,n] = sum_k A[m,k]*W[n,k] + bias[n] ----------------
#define BK 32

template<bool OUT_F32>
__global__ __launch_bounds__(256, 2)
void gemm_nt(const bf16_t* __restrict__ A,
             const bf16_t* __restrict__ W0, const bf16_t* __restrict__ W1,
             const bf16_t* __restrict__ W2,
             const float* __restrict__ b0, const float* __restrict__ b1,
             const float* __restrict__ b2,
             bf16_t* O0, bf16_t* O1, bf16_t* O2, float* OF,
             int nbPer, int vTrans)
{
  __shared__ __align__(16) bf16_t As[128 * BK];
  __shared__ __align__(16) bf16_t Bs[128 * BK];
  const int t = threadIdx.x, w = t >> 6, lane = t & 63;
  const int l15 = lane & 15, q4 = lane >> 4;
  const int wsel = blockIdx.x / nbPer, nb = blockIdx.x % nbPer;
  const bf16_t* Wm = (wsel == 0) ? W0 : ((wsel == 1) ? W1 : W2);
  const float* bias = (wsel == 0) ? b0 : ((wsel == 1) ? b1 : b2);
  bf16_t* Om = (wsel == 0) ? O0 : ((wsel == 1) ? O1 : O2);
  const int m0 = blockIdx.y * 128;
  const int n0 = nb * 128;
  const int wm = (w >> 1) * 64, wn = (w & 1) * 64;

  floatx4 acc[4][4];
#pragma unroll
  for (int mi = 0; mi < 4; ++mi)
#pragma unroll
    for (int ni = 0; ni < 4; ++ni) acc[mi][ni] = (floatx4){0.f, 0.f, 0.f, 0.f};

  const int ch0 = w * 128 + lane;
  for (int k0 = 0; k0 < 1024; k0 += BK) {
#pragma unroll
    for (int c = 0; c < 2; ++c) {
      int chunk = ch0 + c * 64;           // 0..511
      int row = chunk >> 2, seg = chunk & 3;
      async16(A  + (size_t)(m0 + row) * 1024 + k0 + seg * 8, &As[chunk * 8]);
      async16(Wm + (size_t)(n0 + row) * 1024 + k0 + seg * 8, &Bs[chunk * 8]);
    }
    __syncthreads();

    bf16x8 af[4], bfr[4];
#pragma unroll
    for (int i = 0; i < 4; ++i) {
      af[i]  = *(const bf16x8*)&As[(wm + i * 16 + l15) * BK + q4 * 8];
      bfr[i] = *(const bf16x8*)&Bs[(wn + i * 16 + l15) * BK + q4 * 8];
    }
#pragma unroll
    for (int mi = 0; mi < 4; ++mi)
#pragma unroll
      for (int ni = 0; ni < 4; ++ni)
        acc[mi][ni] = __builtin_amdgcn_mfma_f32_16x16x32_bf16(af[mi], bfr[ni], acc[mi][ni], 0, 0, 0);
    __syncthreads();
  }

  // epilogue; C/D layout: col = lane&15, row = (lane>>4)*4 + reg
#pragma unroll
  for (int mi = 0; mi < 4; ++mi) {
#pragma unroll
    for (int ni = 0; ni < 4; ++ni) {
      const int col = n0 + wn + ni * 16 + l15;
      const float bv = bias[col];
      if (OUT_F32) {
#pragma unroll
        for (int r = 0; r < 4; ++r) {
          int row = m0 + wm + mi * 16 + q4 * 4 + r;
          OF[(size_t)row * 1024 + col] = acc[mi][ni][r] + bv;
        }
      } else if (vTrans && wsel == 2) {
        // V transposed: Vt[b][d][t]; lane holds 4 consecutive t -> 8B store
        int rowg = m0 + wm + mi * 16 + q4 * 4;
        int bb = rowg >> 11, tt = rowg & 2047;
        bf16x4 pk;
#pragma unroll
        for (int r = 0; r < 4; ++r) pk[r] = (bf16_t)(acc[mi][ni][r] + bv);
        *(bf16x4*)(Om + (size_t)(bb * 1024 + col) * 2048 + tt) = pk;
      } else {
#pragma unroll
        for (int r = 0; r < 4; ++r) {
          int row = m0 + wm + mi * 16 + q4 * 4 + r;
          Om[(size_t)row * 1024 + col] = (bf16_t)(acc[mi][ni][r] + bv);
        }
      }
    }
  }
}

// ---------------- flash attention: single-wave blocks, register-pipelined ----------------
// 4096 blocks x 64 threads: block = 1 wave owning 16 q rows (tile = blockIdx>>5, bh = &31).
// S^T = K.Q^T; P transposed through a 2.3KB per-block LDS scratch; l via P.ones MFMA;
// fixed-max softmax (scores bounded). K fragments register-double-buffered: kf(jt+1)
// issued BEFORE the lgkm wait (which is a code-motion barrier) so global latency spans
// a full iteration; V issued at iteration top, consumed after softmax. exp via raw
// v_exp_f32; P->bf16 by truncation via v_perm_b32. Causal mask only on diagonal iter.
__global__ void attn_kernel(const bf16_t* __restrict__ Qb, const bf16_t* __restrict__ Kb,
                            const bf16_t* __restrict__ Vt, bf16_t* __restrict__ AO)
{
  __shared__ __align__(16) bf16_t Ps[16][72];

  const int lane = threadIdx.x;          // blockDim.x = 64
  const int l15 = lane & 15, q4 = lane >> 4;
  const int bh = blockIdx.x & 31, tile = blockIdx.x >> 5;   // tile 0..127
  const int b = bh >> 4, h = bh & 15;
  const int r0 = tile * 16;
  const int nIter = (tile >> 2) + 1;
  const int dq = (tile & 3) * 16;        // r0 - 64*(nIter-1)

  const float C1 = 0.125f * LOG2E;
  const float CL = LOG2E;
  const float Er[4] = {1.0f, 2.71828182846f, 7.38905609893f, 20.0855369232f};

  // Q B-frag: n=i=l15, k=d=q4*8+e (+32 for kk=1)
  const bf16_t* qp = Qb + ((size_t)(b * 2048 + r0 + l15)) * 1024 + h * 64 + q4 * 8;
  const bf16x8 qf0 = *(const bf16x8*)qp;
  const bf16x8 qf1 = *(const bf16x8*)(qp + 32);

  const bf16_t* kbase = Kb + ((size_t)b * 2048) * 1024 + h * 64 + q4 * 8;
  const bf16_t* vbase = Vt + ((size_t)(b * 1024 + h * 64)) * 2048 + q4 * 8;

  floatx4 o_acc[4], lsum;
  lsum = (floatx4){0.f, 0.f, 0.f, 0.f};
#pragma unroll
  for (int dt = 0; dt < 4; ++dt) o_acc[dt] = (floatx4){0.f, 0.f, 0.f, 0.f};
  bf16x8 ones;
#pragma unroll
  for (int e = 0; e < 8; ++e) ones[e] = (bf16_t)1.0f;

  auto loadK = [&](bf16x8 (&kf)[4][2], int jt) {
#pragma unroll
    for (int mt = 0; mt < 4; ++mt) {
      const bf16_t* kp = kbase + (unsigned)(mt * 16 + l15) * 1024u + (unsigned)jt * 65536u;
      kf[mt][0] = *(const bf16x8*)kp;
      kf[mt][1] = *(const bf16x8*)(kp + 32);
    }
  };

  auto step = [&](bf16x8 (&kc)[4][2], bf16x8 (&kn)[4][2], int jt) {
    // V for this tile, issued early (consumed after softmax, ~400 cyc later)
    bf16x8 vf[4][2];
#pragma unroll
    for (int dt = 0; dt < 4; ++dt) {
      const bf16_t* vp = vbase + (unsigned)(dt * 16 + l15) * 2048u + (unsigned)jt * 64u;
      vf[dt][0] = *(const bf16x8*)vp;
      vf[dt][1] = *(const bf16x8*)(vp + 32);
    }
    // K for NEXT tile, issued before the lgkm code-motion barrier below
    if (jt + 1 < nIter) loadK(kn, jt + 1);

    const bool diag = (jt == nIter - 1);
    // dm_base = CL*(j0 + q4*4 - i),  i = r0 + l15
    const float dm_base = (float)(jt * 64 + q4 * 4 - r0 - l15) * CL;

#pragma unroll
    for (int mt = 0; mt < 4; ++mt) {
      // S^T = K.Q^T: C col=i=l15, row(j-local)=mt*16+q4*4+r
      floatx4 s4 = __builtin_amdgcn_mfma_f32_16x16x32_bf16(kc[mt][0], qf0,
                       (floatx4){0.f, 0.f, 0.f, 0.f}, 0, 0, 0);
      s4 = __builtin_amdgcn_mfma_f32_16x16x32_bf16(kc[mt][1], qf1, s4, 0, 0, 0);
      const float dmm = dm_base + (float)(mt * 16) * CL;
      float p[4];
#pragma unroll
      for (int r = 0; r < 4; ++r) {
        float v = EXP2(fmaf(s4[r], C1, dmm)) * Er[r];
        if (diag && (mt * 16 + q4 * 4 + r) > (dq + l15)) v = 0.f;
        p[r] = v;
      }
      uint2 pk2;
      pk2.x = pack_bf16_trunc(p[0], p[1]);
      pk2.y = pack_bf16_trunc(p[2], p[3]);
      *(uint2*)&Ps[l15][mt * 16 + q4 * 4] = pk2;   // 4 contiguous j
    }

    __builtin_amdgcn_s_waitcnt(0xC07F);  // lgkmcnt(0): own-wave P writes visible

    // O += P.V and l += P.ones  (pf A-frag: m=i=l15, k=j)
    bf16x8 pf0 = *(const bf16x8*)&Ps[l15][q4 * 8];
    bf16x8 pf1 = *(const bf16x8*)&Ps[l15][32 + q4 * 8];
    lsum = __builtin_amdgcn_mfma_f32_16x16x32_bf16(pf0, ones, lsum, 0, 0, 0);
    lsum = __builtin_amdgcn_mfma_f32_16x16x32_bf16(pf1, ones, lsum, 0, 0, 0);
#pragma unroll
    for (int dt = 0; dt < 4; ++dt) {
      o_acc[dt] = __builtin_amdgcn_mfma_f32_16x16x32_bf16(pf0, vf[dt][0], o_acc[dt], 0, 0, 0);
      o_acc[dt] = __builtin_amdgcn_mfma_f32_16x16x32_bf16(pf1, vf[dt][1], o_acc[dt], 0, 0, 0);
    }
  };

  bf16x8 kfA[4][2], kfB[4][2];
  loadK(kfA, 0);
  int jt = 0;
  while (true) {
    step(kfA, kfB, jt);
    if (++jt >= nIter) break;
    step(kfB, kfA, jt);
    if (++jt >= nIter) break;
  }

  // normalize & store: o_acc row=i-local=q4*4+r, col=d=dt*16+l15; lsum rows match
  floatx4 inv;
#pragma unroll
  for (int r = 0; r < 4; ++r) inv[r] = 1.0f / lsum[r];
#pragma unroll
  for (int dt = 0; dt < 4; ++dt)
#pragma unroll
    for (int r = 0; r < 4; ++r) {
      int i = r0 + q4 * 4 + r;
      AO[((size_t)(b * 2048 + i)) * 1024 + h * 64 + dt * 16 + l15] =
          (bf16_t)(o_acc[dt][r] * inv[r]);
    }
}

// ---------------- launch ----------------
extern "C" void kernel_launch(void* const* d_in, const int* in_sizes, int n_in,
                              void* d_out, int out_size, void* d_ws, size_t ws_size,
                              hipStream_t stream) {
  const float* x  = (const float*)d_in[0];
  const float* Wq = (const float*)d_in[1];
  const float* bq = (const float*)d_in[2];
  const float* Wk = (const float*)d_in[3];
  const float* bk = (const float*)d_in[4];
  const float* Wv = (const float*)d_in[5];
  const float* bv = (const float*)d_in[6];
  const float* Wo = (const float*)d_in[7];
  const float* bo = (const float*)d_in[8];

  char* ws = (char*)d_ws;                      // needs >= 48 MB
  bf16_t* xb  = (bf16_t*)(ws);                 //  8 MB
  bf16_t* wqb = (bf16_t*)(ws + (8u  << 20));   //  2 MB (wq..wo contiguous)
  bf16_t* wkb = (bf16_t*)(ws + (10u << 20));
  bf16_t* wvb = (bf16_t*)(ws + (12u << 20));
  bf16_t* wob = (bf16_t*)(ws + (14u << 20));
  bf16_t* Qb  = (bf16_t*)(ws + (16u << 20));   //  8 MB  [b,t,h,d]
  bf16_t* Kb  = (bf16_t*)(ws + (24u << 20));   //  8 MB  [b,t,h,d]
  bf16_t* Vtb = (bf16_t*)(ws + (32u << 20));   //  8 MB  [b,h*d,t]
  bf16_t* AOb = (bf16_t*)(ws + (40u << 20));   //  8 MB  [b,t,h,d]

  castall<<<8192, 256, 0, stream>>>(x, Wq, Wk, Wv, Wo, xb, wqb);

  gemm_nt<false><<<dim3(24, 32), 256, 0, stream>>>(
      xb, wqb, wkb, wvb, bq, bk, bv, Qb, Kb, Vtb, nullptr, 8, 1);

  attn_kernel<<<4096, 64, 0, stream>>>(Qb, Kb, Vtb, AOb);

  gemm_nt<true><<<dim3(8, 32), 256, 0, stream>>>(
      AOb, wob, wob, wob, bo, bo, bo, nullptr, nullptr, nullptr, (float*)d_out, 8, 0);
}

// Round 6
// 184.424 us; speedup vs baseline: 1.7058x; 1.7058x over previous
//
#include <hip/hip_runtime.h>
#include <hip/hip_bf16.h>
#include <math.h>

// B=2, T=2048, D=1024, H=16, hd=64, ALPHA=1 (decay = -(i-j))
// Pipeline: fused cast f32->bf16 -> fused QKV NT-GEMM (V transposed) -> flash attn -> out GEMM (f32)

typedef __bf16 bf16_t;
typedef bf16_t bf16x8 __attribute__((ext_vector_type(8)));
typedef bf16_t bf16x4 __attribute__((ext_vector_type(4)));
typedef float  floatx4 __attribute__((ext_vector_type(4)));

#define LOG2E 1.44269504088896f

#if __has_builtin(__builtin_amdgcn_exp2f)
#define EXP2(x) __builtin_amdgcn_exp2f(x)
#else
#define EXP2(x) exp2f(x)
#endif

__device__ __forceinline__ void async16(const bf16_t* g, bf16_t* l) {
  __builtin_amdgcn_global_load_lds(
      (const __attribute__((address_space(1))) unsigned int*)g,
      (__attribute__((address_space(3))) unsigned int*)l, 16, 0, 0);
}

// pack two f32 into bf16x2 by truncation (1 v_perm_b32); P>=0 -> rel err <= 2^-8
__device__ __forceinline__ unsigned pack_bf16_trunc(float lo, float hi) {
  return __builtin_amdgcn_perm(__builtin_bit_cast(unsigned, hi),
                               __builtin_bit_cast(unsigned, lo), 0x07060302u);
}

// ---------------- fused cast kernel ----------------
__global__ void castall(const float* __restrict__ x,
                        const float* __restrict__ wq, const float* __restrict__ wk,
                        const float* __restrict__ wv, const float* __restrict__ wo,
                        bf16_t* __restrict__ xb, bf16_t* __restrict__ wdst) {
  int i = blockIdx.x * blockDim.x + threadIdx.x;  // 0 .. 2097151
  const float* src;
  bf16_t* dst;
  if (i < 1048576) {
    src = x + (size_t)i * 4;
    dst = xb + (size_t)i * 4;
  } else {
    int i2 = i - 1048576;
    int wsel = i2 >> 18;
    int off = i2 & 262143;
    const float* wsrc = (wsel == 0) ? wq : (wsel == 1) ? wk : (wsel == 2) ? wv : wo;
    src = wsrc + (size_t)off * 4;
    dst = wdst + (size_t)i2 * 4;
  }
  const float4 f = *(const float4*)src;
  bf16x4 o;
  o[0] = (bf16_t)f.x; o[1] = (bf16_t)f.y; o[2] = (bf16_t)f.z; o[3] = (bf16_t)f.w;
  *(bf16x4*)dst = o;
}

// ---------------- NT GEMM: C[m,n] = sum_k A[m,k]*W[n,k] + bias[n] ----------------
#define BK 32

template<bool OUT_F32>
__global__ __launch_bounds__(256, 2)
void gemm_nt(const bf16_t* __restrict__ A,
             const bf16_t* __restrict__ W0, const bf16_t* __restrict__ W1,
             const bf16_t* __restrict__ W2,
             const float* __restrict__ b0, const float* __restrict__ b1,
             const float* __restrict__ b2,
             bf16_t* O0, bf16_t* O1, bf16_t* O2, float* OF,
             int nbPer, int vTrans)
{
  __shared__ __align__(16) bf16_t As[128 * BK];
  __shared__ __align__(16) bf16_t Bs[128 * BK];
  const int t = threadIdx.x, w = t >> 6, lane = t & 63;
  const int l15 = lane & 15, q4 = lane >> 4;
  const int wsel = blockIdx.x / nbPer, nb = blockIdx.x % nbPer;
  const bf16_t* Wm = (wsel == 0) ? W0 : ((wsel == 1) ? W1 : W2);
  const float* bias = (wsel == 0) ? b0 : ((wsel == 1) ? b1 : b2);
  bf16_t* Om = (wsel == 0) ? O0 : ((wsel == 1) ? O1 : O2);
  const int m0 = blockIdx.y * 128;
  const int n0 = nb * 128;
  const int wm = (w >> 1) * 64, wn = (w & 1) * 64;

  floatx4 acc[4][4];
#pragma unroll
  for (int mi = 0; mi < 4; ++mi)
#pragma unroll
    for (int ni = 0; ni < 4; ++ni) acc[mi][ni] = (floatx4){0.f, 0.f, 0.f, 0.f};

  const int ch0 = w * 128 + lane;
  for (int k0 = 0; k0 < 1024; k0 += BK) {
#pragma unroll
    for (int c = 0; c < 2; ++c) {
      int chunk = ch0 + c * 64;           // 0..511
      int row = chunk >> 2, seg = chunk & 3;
      async16(A  + (size_t)(m0 + row) * 1024 + k0 + seg * 8, &As[chunk * 8]);
      async16(Wm + (size_t)(n0 + row) * 1024 + k0 + seg * 8, &Bs[chunk * 8]);
    }
    __syncthreads();

    bf16x8 af[4], bfr[4];
#pragma unroll
    for (int i = 0; i < 4; ++i) {
      af[i]  = *(const bf16x8*)&As[(wm + i * 16 + l15) * BK + q4 * 8];
      bfr[i] = *(const bf16x8*)&Bs[(wn + i * 16 + l15) * BK + q4 * 8];
    }
#pragma unroll
    for (int mi = 0; mi < 4; ++mi)
#pragma unroll
      for (int ni = 0; ni < 4; ++ni)
        acc[mi][ni] = __builtin_amdgcn_mfma_f32_16x16x32_bf16(af[mi], bfr[ni], acc[mi][ni], 0, 0, 0);
    __syncthreads();
  }

  // epilogue; C/D layout: col = lane&15, row = (lane>>4)*4 + reg
#pragma unroll
  for (int mi = 0; mi < 4; ++mi) {
#pragma unroll
    for (int ni = 0; ni < 4; ++ni) {
      const int col = n0 + wn + ni * 16 + l15;
      const float bv = bias[col];
      if (OUT_F32) {
#pragma unroll
        for (int r = 0; r < 4; ++r) {
          int row = m0 + wm + mi * 16 + q4 * 4 + r;
          OF[(size_t)row * 1024 + col] = acc[mi][ni][r] + bv;
        }
      } else if (vTrans && wsel == 2) {
        // V transposed: Vt[b][d][t]; lane holds 4 consecutive t -> 8B store
        int rowg = m0 + wm + mi * 16 + q4 * 4;
        int bb = rowg >> 11, tt = rowg & 2047;
        bf16x4 pk;
#pragma unroll
        for (int r = 0; r < 4; ++r) pk[r] = (bf16_t)(acc[mi][ni][r] + bv);
        *(bf16x4*)(Om + (size_t)(bb * 1024 + col) * 2048 + tt) = pk;
      } else {
#pragma unroll
        for (int r = 0; r < 4; ++r) {
          int row = m0 + wm + mi * 16 + q4 * 4 + r;
          Om[(size_t)row * 1024 + col] = (bf16_t)(acc[mi][ni][r] + bv);
        }
      }
    }
  }
}

// ---------------- flash attention: LDS-staged K/V, 4 blocks/CU, heavy-first ----------------
// Grid 1024 (32 qb x 32 bh), qb descending (heavy first). Block = 4 waves; wave w owns
// q rows [qb*64+w*16, +16). K tile [j][d] and V tile [d][j] staged once per j-tile into
// single-buffered LDS (16 KB) with 16B-chunk XOR swizzle; 2 barriers/iter (m97 pattern),
// hidden by 4 resident blocks/CU. S^T = K.Q^T so P transposes through per-wave LDS with
// packed b64 writes; l via P.ones MFMA; fixed-max softmax (scores bounded); raw v_exp_f32
// + truncation bf16 pack. No register double-buffering (R5 spill lesson).
__global__ __launch_bounds__(256, 4)
void attn_kernel(const bf16_t* __restrict__ Qb, const bf16_t* __restrict__ Kb,
                 const bf16_t* __restrict__ Vt, bf16_t* __restrict__ AO)
{
  __shared__ __align__(16) bf16_t Ks[64 * 64];
  __shared__ __align__(16) bf16_t Vs[64 * 64];
  __shared__ __align__(16) bf16_t Ps[4][16][72];

  const int t = threadIdx.x, w = t >> 6, lane = t & 63;
  const int l15 = lane & 15, q4 = lane >> 4;
  const int bh = blockIdx.x & 31, qz = blockIdx.x >> 5;
  const int qb = 31 - qz;                 // heavy blocks first
  const int b = bh >> 4, h = bh & 15;
  const int i0 = qb * 64;
  const int nIter = qb + 1;

  const float C1 = 0.125f * LOG2E;        // (1/sqrt(64)) * log2e
  const float CL = LOG2E;
  const float Er[4] = {1.0f, 2.71828182846f, 7.38905609893f, 20.0855369232f};

  // Q B-frag (n=i=l15 within strip, k=d=q4*8+e), i = i0 + w*16 + l15
  const bf16_t* qp = Qb + ((size_t)(b * 2048 + i0 + w * 16 + l15)) * 1024 + h * 64 + q4 * 8;
  const bf16x8 qf0 = *(const bf16x8*)qp;
  const bf16x8 qf1 = *(const bf16x8*)(qp + 32);

  floatx4 o_acc[4], lsum;
  lsum = (floatx4){0.f, 0.f, 0.f, 0.f};
#pragma unroll
  for (int dt = 0; dt < 4; ++dt) o_acc[dt] = (floatx4){0.f, 0.f, 0.f, 0.f};
  bf16x8 ones;
#pragma unroll
  for (int e = 0; e < 8; ++e) ones[e] = (bf16_t)1.0f;

  // decay: dm[mt] = CL*(j - i) at r=0; j = jt*64 + mt*16 + q4*4, i = i0 + w*16 + l15
  float dm[4];
#pragma unroll
  for (int mt = 0; mt < 4; ++mt)
    dm[mt] = (float)(mt * 16 + q4 * 4 - w * 16 - l15 - i0) * CL;
  const int relMask = w * 16 + l15;       // i-local within the 64-row q-block

  for (int jt = 0; jt < nIter; ++jt) {
    // ---- stage K tile [j][d] and V tile [d][j], XOR-swizzled at 16B granularity
#pragma unroll
    for (int c = 0; c < 2; ++c) {
      int chunk = w * 128 + c * 64 + lane;   // 0..511
      int row = chunk >> 3, s = chunk & 7;
      int sg = s ^ (row & 7);
      async16(Kb + ((size_t)(b * 2048 + jt * 64 + row)) * 1024 + h * 64 + sg * 8, &Ks[chunk * 8]);
      async16(Vt + ((size_t)(b * 1024 + h * 64 + row)) * 2048 + jt * 64 + sg * 8, &Vs[chunk * 8]);
    }
    __syncthreads();   // vmcnt drain: tile ready

    const bool diag = (jt == qb);
#pragma unroll
    for (int mt = 0; mt < 4; ++mt) {
      // S^T = K.Q^T: A = Ks row j=mt*16+l15 (k=d), B = qf; C: col=i=l15, row=j=q4*4+r
      int row = mt * 16 + l15;
      int s0 = q4 ^ (row & 7);
      int s1 = (4 + q4) ^ (row & 7);
      bf16x8 kf0 = *(const bf16x8*)&Ks[row * 64 + s0 * 8];
      bf16x8 kf1 = *(const bf16x8*)&Ks[row * 64 + s1 * 8];
      floatx4 s4 = __builtin_amdgcn_mfma_f32_16x16x32_bf16(kf0, qf0,
                       (floatx4){0.f, 0.f, 0.f, 0.f}, 0, 0, 0);
      s4 = __builtin_amdgcn_mfma_f32_16x16x32_bf16(kf1, qf1, s4, 0, 0, 0);

      float p[4];
#pragma unroll
      for (int r = 0; r < 4; ++r) {
        float v = EXP2(fmaf(s4[r], C1, dm[mt])) * Er[r];
        if (diag && (mt * 16 + q4 * 4 + r) > relMask) v = 0.f;
        p[r] = v;
      }
      uint2 pk2;
      pk2.x = pack_bf16_trunc(p[0], p[1]);
      pk2.y = pack_bf16_trunc(p[2], p[3]);
      *(uint2*)&Ps[w][l15][mt * 16 + q4 * 4] = pk2;  // P^T rows j, packed 4-contig
      dm[mt] += 64.0f * CL;
    }

    __builtin_amdgcn_s_waitcnt(0xC07F);  // lgkmcnt(0): own-wave P writes visible

    // ---- O += P.V and l += P.ones (A=pf m=i=l15, k=j; B=Vs rows d, k=j)
    bf16x8 pf0 = *(const bf16x8*)&Ps[w][l15][q4 * 8];
    bf16x8 pf1 = *(const bf16x8*)&Ps[w][l15][32 + q4 * 8];
    lsum = __builtin_amdgcn_mfma_f32_16x16x32_bf16(pf0, ones, lsum, 0, 0, 0);
    lsum = __builtin_amdgcn_mfma_f32_16x16x32_bf16(pf1, ones, lsum, 0, 0, 0);
#pragma unroll
    for (int dt = 0; dt < 4; ++dt) {
      int row = dt * 16 + l15;
      int s0 = q4 ^ (row & 7);
      int s1 = (4 + q4) ^ (row & 7);
      bf16x8 vf0 = *(const bf16x8*)&Vs[row * 64 + s0 * 8];
      bf16x8 vf1 = *(const bf16x8*)&Vs[row * 64 + s1 * 8];
      o_acc[dt] = __builtin_amdgcn_mfma_f32_16x16x32_bf16(pf0, vf0, o_acc[dt], 0, 0, 0);
      o_acc[dt] = __builtin_amdgcn_mfma_f32_16x16x32_bf16(pf1, vf1, o_acc[dt], 0, 0, 0);
    }
    __syncthreads();   // all waves done reading Ks/Vs before next stage
  }

  // ---- normalize & store: o_acc row=i=q4*4+r (in strip), col=d=dt*16+l15
  floatx4 inv;
#pragma unroll
  for (int r = 0; r < 4; ++r) inv[r] = 1.0f / lsum[r];
#pragma unroll
  for (int dt = 0; dt < 4; ++dt)
#pragma unroll
    for (int r = 0; r < 4; ++r) {
      int i = i0 + w * 16 + q4 * 4 + r;
      AO[((size_t)(b * 2048 + i)) * 1024 + h * 64 + dt * 16 + l15] =
          (bf16_t)(o_acc[dt][r] * inv[r]);
    }
}

// ---------------- launch ----------------
extern "C" void kernel_launch(void* const* d_in, const int* in_sizes, int n_in,
                              void* d_out, int out_size, void* d_ws, size_t ws_size,
                              hipStream_t stream) {
  const float* x  = (const float*)d_in[0];
  const float* Wq = (const float*)d_in[1];
  const float* bq = (const float*)d_in[2];
  const float* Wk = (const float*)d_in[3];
  const float* bk = (const float*)d_in[4];
  const float* Wv = (const float*)d_in[5];
  const float* bv = (const float*)d_in[6];
  const float* Wo = (const float*)d_in[7];
  const float* bo = (const float*)d_in[8];

  char* ws = (char*)d_ws;                      // needs >= 48 MB
  bf16_t* xb  = (bf16_t*)(ws);                 //  8 MB
  bf16_t* wqb = (bf16_t*)(ws + (8u  << 20));   //  2 MB (wq..wo contiguous)
  bf16_t* wkb = (bf16_t*)(ws + (10u << 20));
  bf16_t* wvb = (bf16_t*)(ws + (12u << 20));
  bf16_t* wob = (bf16_t*)(ws + (14u << 20));
  bf16_t* Qb  = (bf16_t*)(ws + (16u << 20));   //  8 MB  [b,t,h,d]
  bf16_t* Kb  = (bf16_t*)(ws + (24u << 20));   //  8 MB  [b,t,h,d]
  bf16_t* Vtb = (bf16_t*)(ws + (32u << 20));   //  8 MB  [b,h*d,t]
  bf16_t* AOb = (bf16_t*)(ws + (40u << 20));   //  8 MB  [b,t,h,d]

  castall<<<8192, 256, 0, stream>>>(x, Wq, Wk, Wv, Wo, xb, wqb);

  gemm_nt<false><<<dim3(24, 32), 256, 0, stream>>>(
      xb, wqb, wkb, wvb, bq, bk, bv, Qb, Kb, Vtb, nullptr, 8, 1);

  attn_kernel<<<1024, 256, 0, stream>>>(Qb, Kb, Vtb, AOb);

  gemm_nt<true><<<dim3(8, 32), 256, 0, stream>>>(
      AOb, wob, wob, wob, bo, bo, bo, nullptr, nullptr, nullptr, (float*)d_out, 8, 0);
}

// Round 7
// 184.357 us; speedup vs baseline: 1.7064x; 1.0004x over previous
//
#include <hip/hip_runtime.h>
#include <hip/hip_bf16.h>
#include <math.h>

// B=2, T=2048, D=1024, H=16, hd=64, ALPHA=1 (decay = -(i-j))
// Pipeline: fused cast f32->bf16 -> fused QKV NT-GEMM (V transposed) -> flash attn -> out GEMM (f32)

typedef __bf16 bf16_t;
typedef bf16_t bf16x8 __attribute__((ext_vector_type(8)));
typedef bf16_t bf16x4 __attribute__((ext_vector_type(4)));
typedef float  floatx4 __attribute__((ext_vector_type(4)));

#define LOG2E 1.44269504088896f

#if __has_builtin(__builtin_amdgcn_exp2f)
#define EXP2(x) __builtin_amdgcn_exp2f(x)
#else
#define EXP2(x) exp2f(x)
#endif

__device__ __forceinline__ void async16(const bf16_t* g, bf16_t* l) {
  __builtin_amdgcn_global_load_lds(
      (const __attribute__((address_space(1))) unsigned int*)g,
      (__attribute__((address_space(3))) unsigned int*)l, 16, 0, 0);
}

// pack two f32 into bf16x2 by truncation (1 v_perm_b32); P>=0 -> rel err <= 2^-8
__device__ __forceinline__ unsigned pack_bf16_trunc(float lo, float hi) {
  return __builtin_amdgcn_perm(__builtin_bit_cast(unsigned, hi),
                               __builtin_bit_cast(unsigned, lo), 0x07060302u);
}

// ---------------- fused cast kernel ----------------
__global__ void castall(const float* __restrict__ x,
                        const float* __restrict__ wq, const float* __restrict__ wk,
                        const float* __restrict__ wv, const float* __restrict__ wo,
                        bf16_t* __restrict__ xb, bf16_t* __restrict__ wdst) {
  int i = blockIdx.x * blockDim.x + threadIdx.x;  // 0 .. 2097151
  const float* src;
  bf16_t* dst;
  if (i < 1048576) {
    src = x + (size_t)i * 4;
    dst = xb + (size_t)i * 4;
  } else {
    int i2 = i - 1048576;
    int wsel = i2 >> 18;
    int off = i2 & 262143;
    const float* wsrc = (wsel == 0) ? wq : (wsel == 1) ? wk : (wsel == 2) ? wv : wo;
    src = wsrc + (size_t)off * 4;
    dst = wdst + (size_t)i2 * 4;
  }
  const float4 f = *(const float4*)src;
  bf16x4 o;
  o[0] = (bf16_t)f.x; o[1] = (bf16_t)f.y; o[2] = (bf16_t)f.z; o[3] = (bf16_t)f.w;
  *(bf16x4*)dst = o;
}

// ---------------- NT GEMM: C[m,n] = sum_k A[m,k]*W[n,k] + bias[n] ----------------
#define BK 32

template<bool OUT_F32>
__global__ __launch_bounds__(256, 2)
void gemm_nt(const bf16_t* __restrict__ A,
             const bf16_t* __restrict__ W0, const bf16_t* __restrict__ W1,
             const bf16_t* __restrict__ W2,
             const float* __restrict__ b0, const float* __restrict__ b1,
             const float* __restrict__ b2,
             bf16_t* O0, bf16_t* O1, bf16_t* O2, float* OF,
             int nbPer, int vTrans)
{
  __shared__ __align__(16) bf16_t As[128 * BK];
  __shared__ __align__(16) bf16_t Bs[128 * BK];
  const int t = threadIdx.x, w = t >> 6, lane = t & 63;
  const int l15 = lane & 15, q4 = lane >> 4;
  const int wsel = blockIdx.x / nbPer, nb = blockIdx.x % nbPer;
  const bf16_t* Wm = (wsel == 0) ? W0 : ((wsel == 1) ? W1 : W2);
  const float* bias = (wsel == 0) ? b0 : ((wsel == 1) ? b1 : b2);
  bf16_t* Om = (wsel == 0) ? O0 : ((wsel == 1) ? O1 : O2);
  const int m0 = blockIdx.y * 128;
  const int n0 = nb * 128;
  const int wm = (w >> 1) * 64, wn = (w & 1) * 64;

  floatx4 acc[4][4];
#pragma unroll
  for (int mi = 0; mi < 4; ++mi)
#pragma unroll
    for (int ni = 0; ni < 4; ++ni) acc[mi][ni] = (floatx4){0.f, 0.f, 0.f, 0.f};

  const int ch0 = w * 128 + lane;
  for (int k0 = 0; k0 < 1024; k0 += BK) {
#pragma unroll
    for (int c = 0; c < 2; ++c) {
      int chunk = ch0 + c * 64;           // 0..511
      int row = chunk >> 2, seg = chunk & 3;
      async16(A  + (size_t)(m0 + row) * 1024 + k0 + seg * 8, &As[chunk * 8]);
      async16(Wm + (size_t)(n0 + row) * 1024 + k0 + seg * 8, &Bs[chunk * 8]);
    }
    __syncthreads();

    bf16x8 af[4], bfr[4];
#pragma unroll
    for (int i = 0; i < 4; ++i) {
      af[i]  = *(const bf16x8*)&As[(wm + i * 16 + l15) * BK + q4 * 8];
      bfr[i] = *(const bf16x8*)&Bs[(wn + i * 16 + l15) * BK + q4 * 8];
    }
#pragma unroll
    for (int mi = 0; mi < 4; ++mi)
#pragma unroll
      for (int ni = 0; ni < 4; ++ni)
        acc[mi][ni] = __builtin_amdgcn_mfma_f32_16x16x32_bf16(af[mi], bfr[ni], acc[mi][ni], 0, 0, 0);
    __syncthreads();
  }

  // epilogue; C/D layout: col = lane&15, row = (lane>>4)*4 + reg
#pragma unroll
  for (int mi = 0; mi < 4; ++mi) {
#pragma unroll
    for (int ni = 0; ni < 4; ++ni) {
      const int col = n0 + wn + ni * 16 + l15;
      const float bv = bias[col];
      if (OUT_F32) {
#pragma unroll
        for (int r = 0; r < 4; ++r) {
          int row = m0 + wm + mi * 16 + q4 * 4 + r;
          OF[(size_t)row * 1024 + col] = acc[mi][ni][r] + bv;
        }
      } else if (vTrans && wsel == 2) {
        // V transposed: Vt[b][d][t]; lane holds 4 consecutive t -> 8B store
        int rowg = m0 + wm + mi * 16 + q4 * 4;
        int bb = rowg >> 11, tt = rowg & 2047;
        bf16x4 pk;
#pragma unroll
        for (int r = 0; r < 4; ++r) pk[r] = (bf16_t)(acc[mi][ni][r] + bv);
        *(bf16x4*)(Om + (size_t)(bb * 1024 + col) * 2048 + tt) = pk;
      } else {
#pragma unroll
        for (int r = 0; r < 4; ++r) {
          int row = m0 + wm + mi * 16 + q4 * 4 + r;
          Om[(size_t)row * 1024 + col] = (bf16_t)(acc[mi][ni][r] + bv);
        }
      }
    }
  }
}

// ---------------- flash attention: dbuf LDS K/V, 1 barrier/iter, heavy-first ----------------
// Grid 1024 (32 qb x 32 bh), qb descending. Block = 4 waves; wave w owns q rows
// [qb*64+w*16, +16). K tile [j][d] / V tile [d][j] double-buffered in LDS (2x16 KB,
// XOR-swizzled): stage(jt+1) is issued right AFTER the top-of-iter barrier, so its
// global_load_lds fly during compute(jt) and the next barrier's vmcnt(0) drain finds
// them (mostly) complete -- one barrier per iteration (R2-validated pattern), at
// 3 blocks/CU (launch_bounds(256,3), LDS 41 KB). S^T = K.Q^T -> packed b64 P-transpose
// through per-wave Ps; l via P.ones MFMA; fixed-max softmax; raw v_exp_f32 +
// truncation bf16 pack. No register double-buffering (R5 spill lesson).
__global__ __launch_bounds__(256, 3)
void attn_kernel(const bf16_t* __restrict__ Qb, const bf16_t* __restrict__ Kb,
                 const bf16_t* __restrict__ Vt, bf16_t* __restrict__ AO)
{
  __shared__ __align__(16) bf16_t Ks[2][64 * 64];
  __shared__ __align__(16) bf16_t Vs[2][64 * 64];
  __shared__ __align__(16) bf16_t Ps[4][16][72];

  const int t = threadIdx.x, w = t >> 6, lane = t & 63;
  const int l15 = lane & 15, q4 = lane >> 4;
  const int bh = blockIdx.x & 31, qz = blockIdx.x >> 5;
  const int qb = 31 - qz;                 // heavy blocks first
  const int b = bh >> 4, h = bh & 15;
  const int i0 = qb * 64;
  const int nIter = qb + 1;

  const float C1 = 0.125f * LOG2E;        // (1/sqrt(64)) * log2e
  const float CL = LOG2E;
  const float Er[4] = {1.0f, 2.71828182846f, 7.38905609893f, 20.0855369232f};

  // Q B-frag (n=i=l15 within strip, k=d=q4*8+e), i = i0 + w*16 + l15
  const bf16_t* qp = Qb + ((size_t)(b * 2048 + i0 + w * 16 + l15)) * 1024 + h * 64 + q4 * 8;
  const bf16x8 qf0 = *(const bf16x8*)qp;
  const bf16x8 qf1 = *(const bf16x8*)(qp + 32);

  floatx4 o_acc[4], lsum;
  lsum = (floatx4){0.f, 0.f, 0.f, 0.f};
#pragma unroll
  for (int dt = 0; dt < 4; ++dt) o_acc[dt] = (floatx4){0.f, 0.f, 0.f, 0.f};
  bf16x8 ones;
#pragma unroll
  for (int e = 0; e < 8; ++e) ones[e] = (bf16_t)1.0f;

  // decay: dm[mt] = CL*(j - i) at r=0; j = jt*64 + mt*16 + q4*4, i = i0 + w*16 + l15
  float dm[4];
#pragma unroll
  for (int mt = 0; mt < 4; ++mt)
    dm[mt] = (float)(mt * 16 + q4 * 4 - w * 16 - l15 - i0) * CL;
  const int relMask = w * 16 + l15;       // i-local within the 64-row q-block

  // stage j-tile jt into buffer buf (16B-chunk XOR swizzle)
  auto stage = [&](int buf, int jt) {
#pragma unroll
    for (int c = 0; c < 2; ++c) {
      int chunk = w * 128 + c * 64 + lane;   // 0..511
      int row = chunk >> 3, s = chunk & 7;
      int sg = s ^ (row & 7);
      async16(Kb + ((size_t)(b * 2048 + jt * 64 + row)) * 1024 + h * 64 + sg * 8,
              &Ks[buf][chunk * 8]);
      async16(Vt + ((size_t)(b * 1024 + h * 64 + row)) * 2048 + jt * 64 + sg * 8,
              &Vs[buf][chunk * 8]);
    }
  };

  stage(0, 0);
  for (int jt = 0; jt < nIter; ++jt) {
    __syncthreads();   // vmcnt(0) drain: stage(jt) landed; all waves done with buf jt+1&1
    if (jt + 1 < nIter) stage((jt + 1) & 1, jt + 1);
    const int cur = jt & 1;

    const bool diag = (jt == qb);
#pragma unroll
    for (int mt = 0; mt < 4; ++mt) {
      // S^T = K.Q^T: A = Ks row j=mt*16+l15 (k=d), B = qf; C: col=i=l15, row=j=q4*4+r
      int row = mt * 16 + l15;
      int s0 = q4 ^ (row & 7);
      int s1 = (4 + q4) ^ (row & 7);
      bf16x8 kf0 = *(const bf16x8*)&Ks[cur][row * 64 + s0 * 8];
      bf16x8 kf1 = *(const bf16x8*)&Ks[cur][row * 64 + s1 * 8];
      floatx4 s4 = __builtin_amdgcn_mfma_f32_16x16x32_bf16(kf0, qf0,
                       (floatx4){0.f, 0.f, 0.f, 0.f}, 0, 0, 0);
      s4 = __builtin_amdgcn_mfma_f32_16x16x32_bf16(kf1, qf1, s4, 0, 0, 0);

      float p[4];
#pragma unroll
      for (int r = 0; r < 4; ++r) {
        float v = EXP2(fmaf(s4[r], C1, dm[mt])) * Er[r];
        if (diag && (mt * 16 + q4 * 4 + r) > relMask) v = 0.f;
        p[r] = v;
      }
      uint2 pk2;
      pk2.x = pack_bf16_trunc(p[0], p[1]);
      pk2.y = pack_bf16_trunc(p[2], p[3]);
      *(uint2*)&Ps[w][l15][mt * 16 + q4 * 4] = pk2;  // P^T rows j, packed 4-contig
      dm[mt] += 64.0f * CL;
    }

    __builtin_amdgcn_s_waitcnt(0xC07F);  // lgkmcnt(0): own-wave P writes visible

    // ---- O += P.V and l += P.ones (A=pf m=i=l15, k=j; B=Vs rows d, k=j)
    bf16x8 pf0 = *(const bf16x8*)&Ps[w][l15][q4 * 8];
    bf16x8 pf1 = *(const bf16x8*)&Ps[w][l15][32 + q4 * 8];
    lsum = __builtin_amdgcn_mfma_f32_16x16x32_bf16(pf0, ones, lsum, 0, 0, 0);
    lsum = __builtin_amdgcn_mfma_f32_16x16x32_bf16(pf1, ones, lsum, 0, 0, 0);
#pragma unroll
    for (int dt = 0; dt < 4; ++dt) {
      int row = dt * 16 + l15;
      int s0 = q4 ^ (row & 7);
      int s1 = (4 + q4) ^ (row & 7);
      bf16x8 vf0 = *(const bf16x8*)&Vs[cur][row * 64 + s0 * 8];
      bf16x8 vf1 = *(const bf16x8*)&Vs[cur][row * 64 + s1 * 8];
      o_acc[dt] = __builtin_amdgcn_mfma_f32_16x16x32_bf16(pf0, vf0, o_acc[dt], 0, 0, 0);
      o_acc[dt] = __builtin_amdgcn_mfma_f32_16x16x32_bf16(pf1, vf1, o_acc[dt], 0, 0, 0);
    }
  }

  // ---- normalize & store: o_acc row=i=q4*4+r (in strip), col=d=dt*16+l15
  floatx4 inv;
#pragma unroll
  for (int r = 0; r < 4; ++r) inv[r] = 1.0f / lsum[r];
#pragma unroll
  for (int dt = 0; dt < 4; ++dt)
#pragma unroll
    for (int r = 0; r < 4; ++r) {
      int i = i0 + w * 16 + q4 * 4 + r;
      AO[((size_t)(b * 2048 + i)) * 1024 + h * 64 + dt * 16 + l15] =
          (bf16_t)(o_acc[dt][r] * inv[r]);
    }
}

// ---------------- launch ----------------
extern "C" void kernel_launch(void* const* d_in, const int* in_sizes, int n_in,
                              void* d_out, int out_size, void* d_ws, size_t ws_size,
                              hipStream_t stream) {
  const float* x  = (const float*)d_in[0];
  const float* Wq = (const float*)d_in[1];
  const float* bq = (const float*)d_in[2];
  const float* Wk = (const float*)d_in[3];
  const float* bk = (const float*)d_in[4];
  const float* Wv = (const float*)d_in[5];
  const float* bv = (const float*)d_in[6];
  const float* Wo = (const float*)d_in[7];
  const float* bo = (const float*)d_in[8];

  char* ws = (char*)d_ws;                      // needs >= 48 MB
  bf16_t* xb  = (bf16_t*)(ws);                 //  8 MB
  bf16_t* wqb = (bf16_t*)(ws + (8u  << 20));   //  2 MB (wq..wo contiguous)
  bf16_t* wkb = (bf16_t*)(ws + (10u << 20));
  bf16_t* wvb = (bf16_t*)(ws + (12u << 20));
  bf16_t* wob = (bf16_t*)(ws + (14u << 20));
  bf16_t* Qb  = (bf16_t*)(ws + (16u << 20));   //  8 MB  [b,t,h,d]
  bf16_t* Kb  = (bf16_t*)(ws + (24u << 20));   //  8 MB  [b,t,h,d]
  bf16_t* Vtb = (bf16_t*)(ws + (32u << 20));   //  8 MB  [b,h*d,t]
  bf16_t* AOb = (bf16_t*)(ws + (40u << 20));   //  8 MB  [b,t,h,d]

  castall<<<8192, 256, 0, stream>>>(x, Wq, Wk, Wv, Wo, xb, wqb);

  gemm_nt<false><<<dim3(24, 32), 256, 0, stream>>>(
      xb, wqb, wkb, wvb, bq, bk, bv, Qb, Kb, Vtb, nullptr, 8, 1);

  attn_kernel<<<1024, 256, 0, stream>>>(Qb, Kb, Vtb, AOb);

  gemm_nt<true><<<dim3(8, 32), 256, 0, stream>>>(
      AOb, wob, wob, wob, bo, bo, bo, nullptr, nullptr, nullptr, (float*)d_out, 8, 0);
}

// Round 8
// 179.536 us; speedup vs baseline: 1.7522x; 1.0268x over previous
//
#include <hip/hip_runtime.h>
#include <hip/hip_bf16.h>
#include <math.h>

// B=2, T=2048, D=1024, H=16, hd=64, ALPHA=1 (decay = -(i-j))
// Pipeline: fused cast f32->bf16 -> fused QKV NT-GEMM (V transposed) -> flash attn -> out GEMM (f32)

typedef __bf16 bf16_t;
typedef bf16_t bf16x8 __attribute__((ext_vector_type(8)));
typedef bf16_t bf16x4 __attribute__((ext_vector_type(4)));
typedef float  floatx4 __attribute__((ext_vector_type(4)));

#define LOG2E 1.44269504088896f

#if __has_builtin(__builtin_amdgcn_exp2f)
#define EXP2(x) __builtin_amdgcn_exp2f(x)
#else
#define EXP2(x) exp2f(x)
#endif

__device__ __forceinline__ void async16(const bf16_t* g, bf16_t* l) {
  __builtin_amdgcn_global_load_lds(
      (const __attribute__((address_space(1))) unsigned int*)g,
      (__attribute__((address_space(3))) unsigned int*)l, 16, 0, 0);
}

// pack two f32 into bf16x2 by truncation (1 v_perm_b32); P>=0 -> rel err <= 2^-8
__device__ __forceinline__ unsigned pack_bf16_trunc(float lo, float hi) {
  return __builtin_amdgcn_perm(__builtin_bit_cast(unsigned, hi),
                               __builtin_bit_cast(unsigned, lo), 0x07060302u);
}

// ---------------- fused cast kernel ----------------
__global__ void castall(const float* __restrict__ x,
                        const float* __restrict__ wq, const float* __restrict__ wk,
                        const float* __restrict__ wv, const float* __restrict__ wo,
                        bf16_t* __restrict__ xb, bf16_t* __restrict__ wdst) {
  int i = blockIdx.x * blockDim.x + threadIdx.x;  // 0 .. 2097151
  const float* src;
  bf16_t* dst;
  if (i < 1048576) {
    src = x + (size_t)i * 4;
    dst = xb + (size_t)i * 4;
  } else {
    int i2 = i - 1048576;
    int wsel = i2 >> 18;
    int off = i2 & 262143;
    const float* wsrc = (wsel == 0) ? wq : (wsel == 1) ? wk : (wsel == 2) ? wv : wo;
    src = wsrc + (size_t)off * 4;
    dst = wdst + (size_t)i2 * 4;
  }
  const float4 f = *(const float4*)src;
  bf16x4 o;
  o[0] = (bf16_t)f.x; o[1] = (bf16_t)f.y; o[2] = (bf16_t)f.z; o[3] = (bf16_t)f.w;
  *(bf16x4*)dst = o;
}

// ---------------- NT GEMM: C[m,n] = sum_k A[m,k]*W[n,k] + bias[n] ----------------
// 128x128 tile, BK=64 (32 MFMA per barrier-pair, half the barriers of BK=32).
// LDS tiles XOR-swizzled at 16B granularity (seg ^ row&7): row stride = 128 B = full
// bank span, so swizzle makes every ds_read_b128 2-way (free) instead of 8-way.
#define BK 64

template<bool OUT_F32>
__global__ __launch_bounds__(256, 2)
void gemm_nt(const bf16_t* __restrict__ A,
             const bf16_t* __restrict__ W0, const bf16_t* __restrict__ W1,
             const bf16_t* __restrict__ W2,
             const float* __restrict__ b0, const float* __restrict__ b1,
             const float* __restrict__ b2,
             bf16_t* O0, bf16_t* O1, bf16_t* O2, float* OF,
             int nbPer, int vTrans)
{
  __shared__ __align__(16) bf16_t As[128 * BK];   // 16 KB
  __shared__ __align__(16) bf16_t Bs[128 * BK];   // 16 KB
  const int t = threadIdx.x, w = t >> 6, lane = t & 63;
  const int l15 = lane & 15, q4 = lane >> 4;
  const int wsel = blockIdx.x / nbPer, nb = blockIdx.x % nbPer;
  const bf16_t* Wm = (wsel == 0) ? W0 : ((wsel == 1) ? W1 : W2);
  const float* bias = (wsel == 0) ? b0 : ((wsel == 1) ? b1 : b2);
  bf16_t* Om = (wsel == 0) ? O0 : ((wsel == 1) ? O1 : O2);
  const int m0 = blockIdx.y * 128;
  const int n0 = nb * 128;
  const int wm = (w >> 1) * 64, wn = (w & 1) * 64;

  floatx4 acc[4][4];
#pragma unroll
  for (int mi = 0; mi < 4; ++mi)
#pragma unroll
    for (int ni = 0; ni < 4; ++ni) acc[mi][ni] = (floatx4){0.f, 0.f, 0.f, 0.f};

  // staging: 1024 chunks (16 B) per matrix; chunk = w*256 + c*64 + lane, c=0..3.
  // physical slot chunk&7 holds global seg (chunk&7)^(row&7)  [XOR swizzle]
  const int ch0 = w * 256 + lane;
  for (int k0 = 0; k0 < 1024; k0 += BK) {
#pragma unroll
    for (int c = 0; c < 4; ++c) {
      int chunk = ch0 + c * 64;             // 0..1023
      int row = chunk >> 3;
      int g = (chunk & 7) ^ (row & 7);
      async16(A  + (size_t)(m0 + row) * 1024 + k0 + g * 8, &As[chunk * 8]);
      async16(Wm + (size_t)(n0 + row) * 1024 + k0 + g * 8, &Bs[chunk * 8]);
    }
    __syncthreads();

#pragma unroll
    for (int kk = 0; kk < 2; ++kk) {
      bf16x8 af[4], bfr[4];
#pragma unroll
      for (int i = 0; i < 4; ++i) {
        int ra = wm + i * 16 + l15;
        int rb = wn + i * 16 + l15;
        int pa = (kk * 4 + q4) ^ (ra & 7);
        int pb = (kk * 4 + q4) ^ (rb & 7);
        af[i]  = *(const bf16x8*)&As[ra * BK + pa * 8];
        bfr[i] = *(const bf16x8*)&Bs[rb * BK + pb * 8];
      }
#pragma unroll
      for (int mi = 0; mi < 4; ++mi)
#pragma unroll
        for (int ni = 0; ni < 4; ++ni)
          acc[mi][ni] = __builtin_amdgcn_mfma_f32_16x16x32_bf16(af[mi], bfr[ni], acc[mi][ni], 0, 0, 0);
    }
    __syncthreads();
  }

  // epilogue; C/D layout: col = lane&15, row = (lane>>4)*4 + reg
#pragma unroll
  for (int mi = 0; mi < 4; ++mi) {
#pragma unroll
    for (int ni = 0; ni < 4; ++ni) {
      const int col = n0 + wn + ni * 16 + l15;
      const float bv = bias[col];
      if (OUT_F32) {
#pragma unroll
        for (int r = 0; r < 4; ++r) {
          int row = m0 + wm + mi * 16 + q4 * 4 + r;
          OF[(size_t)row * 1024 + col] = acc[mi][ni][r] + bv;
        }
      } else if (vTrans && wsel == 2) {
        // V transposed: Vt[b][d][t]; lane holds 4 consecutive t -> 8B store
        int rowg = m0 + wm + mi * 16 + q4 * 4;
        int bb = rowg >> 11, tt = rowg & 2047;
        bf16x4 pk;
#pragma unroll
        for (int r = 0; r < 4; ++r) pk[r] = (bf16_t)(acc[mi][ni][r] + bv);
        *(bf16x4*)(Om + (size_t)(bb * 1024 + col) * 2048 + tt) = pk;
      } else {
#pragma unroll
        for (int r = 0; r < 4; ++r) {
          int row = m0 + wm + mi * 16 + q4 * 4 + r;
          Om[(size_t)row * 1024 + col] = (bf16_t)(acc[mi][ni][r] + bv);
        }
      }
    }
  }
}

// ---------------- flash attention: dbuf LDS K/V, 1 barrier/iter, heavy-first ----------------
// Grid 1024 (32 qb x 32 bh), qb descending. Block = 4 waves; wave w owns q rows
// [qb*64+w*16, +16). K tile [j][d] / V tile [d][j] double-buffered in LDS (2x16 KB,
// XOR-swizzled); stage(jt+1) issued right after the top-of-iter barrier. 3 blocks/CU.
// S^T = K.Q^T -> packed b64 P-transpose through per-wave Ps; l via P.ones MFMA;
// fixed-max softmax; raw v_exp_f32 + truncation bf16 pack. Staging addresses hoisted
// to incremented pointers (no per-iter 64-bit mults).
__global__ __launch_bounds__(256, 3)
void attn_kernel(const bf16_t* __restrict__ Qb, const bf16_t* __restrict__ Kb,
                 const bf16_t* __restrict__ Vt, bf16_t* __restrict__ AO)
{
  __shared__ __align__(16) bf16_t Ks[2][64 * 64];
  __shared__ __align__(16) bf16_t Vs[2][64 * 64];
  __shared__ __align__(16) bf16_t Ps[4][16][72];

  const int t = threadIdx.x, w = t >> 6, lane = t & 63;
  const int l15 = lane & 15, q4 = lane >> 4;
  const int bh = blockIdx.x & 31, qz = blockIdx.x >> 5;
  const int qb = 31 - qz;                 // heavy blocks first
  const int b = bh >> 4, h = bh & 15;
  const int i0 = qb * 64;
  const int nIter = qb + 1;

  const float C1 = 0.125f * LOG2E;        // (1/sqrt(64)) * log2e
  const float CL = LOG2E;
  const float Er[4] = {1.0f, 2.71828182846f, 7.38905609893f, 20.0855369232f};

  // Q B-frag (n=i=l15 within strip, k=d=q4*8+e), i = i0 + w*16 + l15
  const bf16_t* qp = Qb + ((size_t)(b * 2048 + i0 + w * 16 + l15)) * 1024 + h * 64 + q4 * 8;
  const bf16x8 qf0 = *(const bf16x8*)qp;
  const bf16x8 qf1 = *(const bf16x8*)(qp + 32);

  floatx4 o_acc[4], lsum;
  lsum = (floatx4){0.f, 0.f, 0.f, 0.f};
#pragma unroll
  for (int dt = 0; dt < 4; ++dt) o_acc[dt] = (floatx4){0.f, 0.f, 0.f, 0.f};
  bf16x8 ones;
#pragma unroll
  for (int e = 0; e < 8; ++e) ones[e] = (bf16_t)1.0f;

  // decay: dm[mt] = CL*(j - i) at r=0; j = jt*64 + mt*16 + q4*4, i = i0 + w*16 + l15
  float dm[4];
#pragma unroll
  for (int mt = 0; mt < 4; ++mt)
    dm[mt] = (float)(mt * 16 + q4 * 4 - w * 16 - l15 - i0) * CL;
  const int relMask = w * 16 + l15;       // i-local within the 64-row q-block

  // staging pointers (2 chunks per thread), incremented per stage (no 64b mults in loop)
  const int chA = w * 128 + lane, chB = chA + 64;
  const int rA = chA >> 3, rB = chB >> 3;
  const int sA = (chA & 7) ^ (rA & 7), sB = (chB & 7) ^ (rB & 7);
  const bf16_t* kpA = Kb + ((size_t)(b * 2048 + rA)) * 1024 + h * 64 + sA * 8;
  const bf16_t* kpB = Kb + ((size_t)(b * 2048 + rB)) * 1024 + h * 64 + sB * 8;
  const bf16_t* vpA = Vt + ((size_t)(b * 1024 + h * 64 + rA)) * 2048 + sA * 8;
  const bf16_t* vpB = Vt + ((size_t)(b * 1024 + h * 64 + rB)) * 2048 + sB * 8;

  auto stage = [&](int buf) {
    async16(kpA, &Ks[buf][chA * 8]);
    async16(kpB, &Ks[buf][chB * 8]);
    async16(vpA, &Vs[buf][chA * 8]);
    async16(vpB, &Vs[buf][chB * 8]);
    kpA += 65536; kpB += 65536;   // next 64 K rows
    vpA += 64;    vpB += 64;      // next 64 j columns
  };

  stage(0);
  for (int jt = 0; jt < nIter; ++jt) {
    __syncthreads();   // vmcnt(0) drain: stage(jt) landed; all waves done with other buf
    if (jt + 1 < nIter) stage((jt + 1) & 1);
    const int cur = jt & 1;

    const bool diag = (jt == qb);
#pragma unroll
    for (int mt = 0; mt < 4; ++mt) {
      // S^T = K.Q^T: A = Ks row j=mt*16+l15 (k=d), B = qf; C: col=i=l15, row=j=q4*4+r
      int row = mt * 16 + l15;
      int s0 = q4 ^ (row & 7);
      int s1 = (4 + q4) ^ (row & 7);
      bf16x8 kf0 = *(const bf16x8*)&Ks[cur][row * 64 + s0 * 8];
      bf16x8 kf1 = *(const bf16x8*)&Ks[cur][row * 64 + s1 * 8];
      floatx4 s4 = __builtin_amdgcn_mfma_f32_16x16x32_bf16(kf0, qf0,
                       (floatx4){0.f, 0.f, 0.f, 0.f}, 0, 0, 0);
      s4 = __builtin_amdgcn_mfma_f32_16x16x32_bf16(kf1, qf1, s4, 0, 0, 0);

      float p[4];
#pragma unroll
      for (int r = 0; r < 4; ++r) {
        float v = EXP2(fmaf(s4[r], C1, dm[mt])) * Er[r];
        if (diag && (mt * 16 + q4 * 4 + r) > relMask) v = 0.f;
        p[r] = v;
      }
      uint2 pk2;
      pk2.x = pack_bf16_trunc(p[0], p[1]);
      pk2.y = pack_bf16_trunc(p[2], p[3]);
      *(uint2*)&Ps[w][l15][mt * 16 + q4 * 4] = pk2;  // P^T rows j, packed 4-contig
      dm[mt] += 64.0f * CL;
    }

    __builtin_amdgcn_s_waitcnt(0xC07F);  // lgkmcnt(0): own-wave P writes visible

    // ---- O += P.V and l += P.ones (A=pf m=i=l15, k=j; B=Vs rows d, k=j)
    bf16x8 pf0 = *(const bf16x8*)&Ps[w][l15][q4 * 8];
    bf16x8 pf1 = *(const bf16x8*)&Ps[w][l15][32 + q4 * 8];
    lsum = __builtin_amdgcn_mfma_f32_16x16x32_bf16(pf0, ones, lsum, 0, 0, 0);
    lsum = __builtin_amdgcn_mfma_f32_16x16x32_bf16(pf1, ones, lsum, 0, 0, 0);
#pragma unroll
    for (int dt = 0; dt < 4; ++dt) {
      int row = dt * 16 + l15;
      int s0 = q4 ^ (row & 7);
      int s1 = (4 + q4) ^ (row & 7);
      bf16x8 vf0 = *(const bf16x8*)&Vs[cur][row * 64 + s0 * 8];
      bf16x8 vf1 = *(const bf16x8*)&Vs[cur][row * 64 + s1 * 8];
      o_acc[dt] = __builtin_amdgcn_mfma_f32_16x16x32_bf16(pf0, vf0, o_acc[dt], 0, 0, 0);
      o_acc[dt] = __builtin_amdgcn_mfma_f32_16x16x32_bf16(pf1, vf1, o_acc[dt], 0, 0, 0);
    }
  }

  // ---- normalize & store: o_acc row=i=q4*4+r (in strip), col=d=dt*16+l15
  floatx4 inv;
#pragma unroll
  for (int r = 0; r < 4; ++r) inv[r] = 1.0f / lsum[r];
#pragma unroll
  for (int dt = 0; dt < 4; ++dt)
#pragma unroll
    for (int r = 0; r < 4; ++r) {
      int i = i0 + w * 16 + q4 * 4 + r;
      AO[((size_t)(b * 2048 + i)) * 1024 + h * 64 + dt * 16 + l15] =
          (bf16_t)(o_acc[dt][r] * inv[r]);
    }
}

// ---------------- launch ----------------
extern "C" void kernel_launch(void* const* d_in, const int* in_sizes, int n_in,
                              void* d_out, int out_size, void* d_ws, size_t ws_size,
                              hipStream_t stream) {
  const float* x  = (const float*)d_in[0];
  const float* Wq = (const float*)d_in[1];
  const float* bq = (const float*)d_in[2];
  const float* Wk = (const float*)d_in[3];
  const float* bk = (const float*)d_in[4];
  const float* Wv = (const float*)d_in[5];
  const float* bv = (const float*)d_in[6];
  const float* Wo = (const float*)d_in[7];
  const float* bo = (const float*)d_in[8];

  char* ws = (char*)d_ws;                      // needs >= 48 MB
  bf16_t* xb  = (bf16_t*)(ws);                 //  8 MB
  bf16_t* wqb = (bf16_t*)(ws + (8u  << 20));   //  2 MB (wq..wo contiguous)
  bf16_t* wkb = (bf16_t*)(ws + (10u << 20));
  bf16_t* wvb = (bf16_t*)(ws + (12u << 20));
  bf16_t* wob = (bf16_t*)(ws + (14u << 20));
  bf16_t* Qb  = (bf16_t*)(ws + (16u << 20));   //  8 MB  [b,t,h,d]
  bf16_t* Kb  = (bf16_t*)(ws + (24u << 20));   //  8 MB  [b,t,h,d]
  bf16_t* Vtb = (bf16_t*)(ws + (32u << 20));   //  8 MB  [b,h*d,t]
  bf16_t* AOb = (bf16_t*)(ws + (40u << 20));   //  8 MB  [b,t,h,d]

  castall<<<8192, 256, 0, stream>>>(x, Wq, Wk, Wv, Wo, xb, wqb);

  gemm_nt<false><<<dim3(24, 32), 256, 0, stream>>>(
      xb, wqb, wkb, wvb, bq, bk, bv, Qb, Kb, Vtb, nullptr, 8, 1);

  attn_kernel<<<1024, 256, 0, stream>>>(Qb, Kb, Vtb, AOb);

  gemm_nt<true><<<dim3(8, 32), 256, 0, stream>>>(
      AOb, wob, wob, wob, bo, bo, bo, nullptr, nullptr, nullptr, (float*)d_out, 8, 0);
}

// Round 9
// 171.591 us; speedup vs baseline: 1.8333x; 1.0463x over previous
//
#include <hip/hip_runtime.h>
#include <hip/hip_bf16.h>
#include <math.h>

// B=2, T=2048, D=1024, H=16, hd=64, ALPHA=1 (decay = -(i-j))
// Pipeline: fused cast f32->bf16 -> fused QKV NT-GEMM (V transposed) -> flash attn -> out GEMM (f32)

typedef __bf16 bf16_t;
typedef bf16_t bf16x8 __attribute__((ext_vector_type(8)));
typedef bf16_t bf16x4 __attribute__((ext_vector_type(4)));
typedef float  floatx4 __attribute__((ext_vector_type(4)));

#define LOG2E 1.44269504088896f

#if __has_builtin(__builtin_amdgcn_exp2f)
#define EXP2(x) __builtin_amdgcn_exp2f(x)
#else
#define EXP2(x) exp2f(x)
#endif

__device__ __forceinline__ void async16(const bf16_t* g, bf16_t* l) {
  __builtin_amdgcn_global_load_lds(
      (const __attribute__((address_space(1))) unsigned int*)g,
      (__attribute__((address_space(3))) unsigned int*)l, 16, 0, 0);
}

// pack two f32 into bf16x2 by truncation (1 v_perm_b32); P>=0 -> rel err <= 2^-8
__device__ __forceinline__ unsigned pack_bf16_trunc(float lo, float hi) {
  return __builtin_amdgcn_perm(__builtin_bit_cast(unsigned, hi),
                               __builtin_bit_cast(unsigned, lo), 0x07060302u);
}

// ---------------- fused cast kernel ----------------
__global__ void castall(const float* __restrict__ x,
                        const float* __restrict__ wq, const float* __restrict__ wk,
                        const float* __restrict__ wv, const float* __restrict__ wo,
                        bf16_t* __restrict__ xb, bf16_t* __restrict__ wdst) {
  int i = blockIdx.x * blockDim.x + threadIdx.x;  // 0 .. 2097151
  const float* src;
  bf16_t* dst;
  if (i < 1048576) {
    src = x + (size_t)i * 4;
    dst = xb + (size_t)i * 4;
  } else {
    int i2 = i - 1048576;
    int wsel = i2 >> 18;
    int off = i2 & 262143;
    const float* wsrc = (wsel == 0) ? wq : (wsel == 1) ? wk : (wsel == 2) ? wv : wo;
    src = wsrc + (size_t)off * 4;
    dst = wdst + (size_t)i2 * 4;
  }
  const float4 f = *(const float4*)src;
  bf16x4 o;
  o[0] = (bf16_t)f.x; o[1] = (bf16_t)f.y; o[2] = (bf16_t)f.z; o[3] = (bf16_t)f.w;
  *(bf16x4*)dst = o;
}

// ---------------- QKV NT GEMM: 128x128 tile, BK=64, XOR-swizzled LDS ----------------
// 768 blocks at 3 blocks/CU (launch_bounds(256,3)) = exactly one dispatch round.
#define BK 64

__global__ __launch_bounds__(256, 3)
void gemm_qkv(const bf16_t* __restrict__ A,
              const bf16_t* __restrict__ W0, const bf16_t* __restrict__ W1,
              const bf16_t* __restrict__ W2,
              const float* __restrict__ b0, const float* __restrict__ b1,
              const float* __restrict__ b2,
              bf16_t* O0, bf16_t* O1, bf16_t* O2)
{
  __shared__ __align__(16) bf16_t As[128 * BK];   // 16 KB
  __shared__ __align__(16) bf16_t Bs[128 * BK];   // 16 KB
  const int t = threadIdx.x, w = t >> 6, lane = t & 63;
  const int l15 = lane & 15, q4 = lane >> 4;
  const int wsel = blockIdx.x >> 3, nb = blockIdx.x & 7;
  const bf16_t* Wm = (wsel == 0) ? W0 : ((wsel == 1) ? W1 : W2);
  const float* bias = (wsel == 0) ? b0 : ((wsel == 1) ? b1 : b2);
  bf16_t* Om = (wsel == 0) ? O0 : ((wsel == 1) ? O1 : O2);
  const int m0 = blockIdx.y * 128;
  const int n0 = nb * 128;
  const int wm = (w >> 1) * 64, wn = (w & 1) * 64;

  floatx4 acc[4][4];
#pragma unroll
  for (int mi = 0; mi < 4; ++mi)
#pragma unroll
    for (int ni = 0; ni < 4; ++ni) acc[mi][ni] = (floatx4){0.f, 0.f, 0.f, 0.f};

  // staging: 1024 chunks (16 B) per matrix; physical slot chunk&7 holds global
  // seg (chunk&7)^(row&7)  [XOR swizzle: row stride 128 B = full bank span]
  const int ch0 = w * 256 + lane;
  for (int k0 = 0; k0 < 1024; k0 += BK) {
#pragma unroll
    for (int c = 0; c < 4; ++c) {
      int chunk = ch0 + c * 64;             // 0..1023
      int row = chunk >> 3;
      int g = (chunk & 7) ^ (row & 7);
      async16(A  + (size_t)(m0 + row) * 1024 + k0 + g * 8, &As[chunk * 8]);
      async16(Wm + (size_t)(n0 + row) * 1024 + k0 + g * 8, &Bs[chunk * 8]);
    }
    __syncthreads();

#pragma unroll
    for (int kk = 0; kk < 2; ++kk) {
      bf16x8 af[4], bfr[4];
#pragma unroll
      for (int i = 0; i < 4; ++i) {
        int ra = wm + i * 16 + l15;
        int rb = wn + i * 16 + l15;
        int pa = (kk * 4 + q4) ^ (ra & 7);
        int pb = (kk * 4 + q4) ^ (rb & 7);
        af[i]  = *(const bf16x8*)&As[ra * BK + pa * 8];
        bfr[i] = *(const bf16x8*)&Bs[rb * BK + pb * 8];
      }
#pragma unroll
      for (int mi = 0; mi < 4; ++mi)
#pragma unroll
        for (int ni = 0; ni < 4; ++ni)
          acc[mi][ni] = __builtin_amdgcn_mfma_f32_16x16x32_bf16(af[mi], bfr[ni], acc[mi][ni], 0, 0, 0);
    }
    __syncthreads();
  }

  // epilogue; C/D layout: col = lane&15, row = (lane>>4)*4 + reg
#pragma unroll
  for (int mi = 0; mi < 4; ++mi) {
#pragma unroll
    for (int ni = 0; ni < 4; ++ni) {
      const int col = n0 + wn + ni * 16 + l15;
      const float bv = bias[col];
      if (wsel == 2) {
        // V transposed: Vt[b][d][t]; lane holds 4 consecutive t -> 8B store
        int rowg = m0 + wm + mi * 16 + q4 * 4;
        int bb = rowg >> 11, tt = rowg & 2047;
        bf16x4 pk;
#pragma unroll
        for (int r = 0; r < 4; ++r) pk[r] = (bf16_t)(acc[mi][ni][r] + bv);
        *(bf16x4*)(Om + (size_t)(bb * 1024 + col) * 2048 + tt) = pk;
      } else {
#pragma unroll
        for (int r = 0; r < 4; ++r) {
          int row = m0 + wm + mi * 16 + q4 * 4 + r;
          Om[(size_t)row * 1024 + col] = (bf16_t)(acc[mi][ni][r] + bv);
        }
      }
    }
  }
}

// ---------------- out NT GEMM: 64x128 tile (f32 out) ----------------
// grid (8, 64) = 512 blocks at 2 blocks/CU = one round, 2x waves/CU vs 128x128.
__global__ __launch_bounds__(256, 2)
void gemm_out(const bf16_t* __restrict__ A, const bf16_t* __restrict__ Wm,
              const float* __restrict__ bias, float* __restrict__ OF)
{
  __shared__ __align__(16) bf16_t As[64 * BK];    //  8 KB
  __shared__ __align__(16) bf16_t Bs[128 * BK];   // 16 KB
  const int t = threadIdx.x, w = t >> 6, lane = t & 63;
  const int l15 = lane & 15, q4 = lane >> 4;
  const int m0 = blockIdx.y * 64;
  const int n0 = blockIdx.x * 128;
  const int wm = (w >> 1) * 32, wn = (w & 1) * 64;

  floatx4 acc[2][4];
#pragma unroll
  for (int mi = 0; mi < 2; ++mi)
#pragma unroll
    for (int ni = 0; ni < 4; ++ni) acc[mi][ni] = (floatx4){0.f, 0.f, 0.f, 0.f};

  for (int k0 = 0; k0 < 1024; k0 += BK) {
    // A: 512 chunks (2/thread); B: 1024 chunks (4/thread); XOR swizzle
    {
      int cA = t;
#pragma unroll
      for (int c = 0; c < 2; ++c) {
        int row = cA >> 3;
        int g = (cA & 7) ^ (row & 7);
        async16(A + (size_t)(m0 + row) * 1024 + k0 + g * 8, &As[cA * 8]);
        cA += 256;
      }
      int cB = t;
#pragma unroll
      for (int c = 0; c < 4; ++c) {
        int row = cB >> 3;
        int g = (cB & 7) ^ (row & 7);
        async16(Wm + (size_t)(n0 + row) * 1024 + k0 + g * 8, &Bs[cB * 8]);
        cB += 256;
      }
    }
    __syncthreads();

#pragma unroll
    for (int kk = 0; kk < 2; ++kk) {
      bf16x8 af[2], bfr[4];
#pragma unroll
      for (int i = 0; i < 2; ++i) {
        int ra = wm + i * 16 + l15;
        int pa = (kk * 4 + q4) ^ (ra & 7);
        af[i] = *(const bf16x8*)&As[ra * BK + pa * 8];
      }
#pragma unroll
      for (int i = 0; i < 4; ++i) {
        int rb = wn + i * 16 + l15;
        int pb = (kk * 4 + q4) ^ (rb & 7);
        bfr[i] = *(const bf16x8*)&Bs[rb * BK + pb * 8];
      }
#pragma unroll
      for (int mi = 0; mi < 2; ++mi)
#pragma unroll
        for (int ni = 0; ni < 4; ++ni)
          acc[mi][ni] = __builtin_amdgcn_mfma_f32_16x16x32_bf16(af[mi], bfr[ni], acc[mi][ni], 0, 0, 0);
    }
    __syncthreads();
  }

#pragma unroll
  for (int mi = 0; mi < 2; ++mi)
#pragma unroll
    for (int ni = 0; ni < 4; ++ni) {
      const int col = n0 + wn + ni * 16 + l15;
      const float bv = bias[col];
#pragma unroll
      for (int r = 0; r < 4; ++r) {
        int row = m0 + wm + mi * 16 + q4 * 4 + r;
        OF[(size_t)row * 1024 + col] = acc[mi][ni][r] + bv;
      }
    }
}

// ---------------- flash attention: dbuf LDS K/V, 1 barrier/iter, heavy-first ----------------
__global__ __launch_bounds__(256, 3)
void attn_kernel(const bf16_t* __restrict__ Qb, const bf16_t* __restrict__ Kb,
                 const bf16_t* __restrict__ Vt, bf16_t* __restrict__ AO)
{
  __shared__ __align__(16) bf16_t Ks[2][64 * 64];
  __shared__ __align__(16) bf16_t Vs[2][64 * 64];
  __shared__ __align__(16) bf16_t Ps[4][16][72];

  const int t = threadIdx.x, w = t >> 6, lane = t & 63;
  const int l15 = lane & 15, q4 = lane >> 4;
  const int bh = blockIdx.x & 31, qz = blockIdx.x >> 5;
  const int qb = 31 - qz;                 // heavy blocks first
  const int b = bh >> 4, h = bh & 15;
  const int i0 = qb * 64;
  const int nIter = qb + 1;

  const float C1 = 0.125f * LOG2E;        // (1/sqrt(64)) * log2e
  const float CL = LOG2E;
  const float Er[4] = {1.0f, 2.71828182846f, 7.38905609893f, 20.0855369232f};

  // Q B-frag (n=i=l15 within strip, k=d=q4*8+e), i = i0 + w*16 + l15
  const bf16_t* qp = Qb + ((size_t)(b * 2048 + i0 + w * 16 + l15)) * 1024 + h * 64 + q4 * 8;
  const bf16x8 qf0 = *(const bf16x8*)qp;
  const bf16x8 qf1 = *(const bf16x8*)(qp + 32);

  floatx4 o_acc[4], lsum;
  lsum = (floatx4){0.f, 0.f, 0.f, 0.f};
#pragma unroll
  for (int dt = 0; dt < 4; ++dt) o_acc[dt] = (floatx4){0.f, 0.f, 0.f, 0.f};
  bf16x8 ones;
#pragma unroll
  for (int e = 0; e < 8; ++e) ones[e] = (bf16_t)1.0f;

  // decay: dm[mt] = CL*(j - i) at r=0; j = jt*64 + mt*16 + q4*4, i = i0 + w*16 + l15
  float dm[4];
#pragma unroll
  for (int mt = 0; mt < 4; ++mt)
    dm[mt] = (float)(mt * 16 + q4 * 4 - w * 16 - l15 - i0) * CL;
  const int relMask = w * 16 + l15;       // i-local within the 64-row q-block

  // staging pointers (2 chunks per thread), incremented per stage
  const int chA = w * 128 + lane, chB = chA + 64;
  const int rA = chA >> 3, rB = chB >> 3;
  const int sA = (chA & 7) ^ (rA & 7), sB = (chB & 7) ^ (rB & 7);
  const bf16_t* kpA = Kb + ((size_t)(b * 2048 + rA)) * 1024 + h * 64 + sA * 8;
  const bf16_t* kpB = Kb + ((size_t)(b * 2048 + rB)) * 1024 + h * 64 + sB * 8;
  const bf16_t* vpA = Vt + ((size_t)(b * 1024 + h * 64 + rA)) * 2048 + sA * 8;
  const bf16_t* vpB = Vt + ((size_t)(b * 1024 + h * 64 + rB)) * 2048 + sB * 8;

  auto stage = [&](int buf) {
    async16(kpA, &Ks[buf][chA * 8]);
    async16(kpB, &Ks[buf][chB * 8]);
    async16(vpA, &Vs[buf][chA * 8]);
    async16(vpB, &Vs[buf][chB * 8]);
    kpA += 65536; kpB += 65536;   // next 64 K rows
    vpA += 64;    vpB += 64;      // next 64 j columns
  };

  stage(0);
  for (int jt = 0; jt < nIter; ++jt) {
    __syncthreads();   // vmcnt(0) drain: stage(jt) landed; all waves done with other buf
    if (jt + 1 < nIter) stage((jt + 1) & 1);
    const int cur = jt & 1;

    const bool diag = (jt == qb);
#pragma unroll
    for (int mt = 0; mt < 4; ++mt) {
      // S^T = K.Q^T: A = Ks row j=mt*16+l15 (k=d), B = qf; C: col=i=l15, row=j=q4*4+r
      int row = mt * 16 + l15;
      int s0 = q4 ^ (row & 7);
      int s1 = (4 + q4) ^ (row & 7);
      bf16x8 kf0 = *(const bf16x8*)&Ks[cur][row * 64 + s0 * 8];
      bf16x8 kf1 = *(const bf16x8*)&Ks[cur][row * 64 + s1 * 8];
      floatx4 s4 = __builtin_amdgcn_mfma_f32_16x16x32_bf16(kf0, qf0,
                       (floatx4){0.f, 0.f, 0.f, 0.f}, 0, 0, 0);
      s4 = __builtin_amdgcn_mfma_f32_16x16x32_bf16(kf1, qf1, s4, 0, 0, 0);

      float p[4];
#pragma unroll
      for (int r = 0; r < 4; ++r) {
        float v = EXP2(fmaf(s4[r], C1, dm[mt])) * Er[r];
        if (diag && (mt * 16 + q4 * 4 + r) > relMask) v = 0.f;
        p[r] = v;
      }
      uint2 pk2;
      pk2.x = pack_bf16_trunc(p[0], p[1]);
      pk2.y = pack_bf16_trunc(p[2], p[3]);
      *(uint2*)&Ps[w][l15][mt * 16 + q4 * 4] = pk2;  // P^T rows j, packed 4-contig
      dm[mt] += 64.0f * CL;
    }

    __builtin_amdgcn_s_waitcnt(0xC07F);  // lgkmcnt(0): own-wave P writes visible

    // ---- O += P.V and l += P.ones (A=pf m=i=l15, k=j; B=Vs rows d, k=j)
    bf16x8 pf0 = *(const bf16x8*)&Ps[w][l15][q4 * 8];
    bf16x8 pf1 = *(const bf16x8*)&Ps[w][l15][32 + q4 * 8];
    lsum = __builtin_amdgcn_mfma_f32_16x16x32_bf16(pf0, ones, lsum, 0, 0, 0);
    lsum = __builtin_amdgcn_mfma_f32_16x16x32_bf16(pf1, ones, lsum, 0, 0, 0);
#pragma unroll
    for (int dt = 0; dt < 4; ++dt) {
      int row = dt * 16 + l15;
      int s0 = q4 ^ (row & 7);
      int s1 = (4 + q4) ^ (row & 7);
      bf16x8 vf0 = *(const bf16x8*)&Vs[cur][row * 64 + s0 * 8];
      bf16x8 vf1 = *(const bf16x8*)&Vs[cur][row * 64 + s1 * 8];
      o_acc[dt] = __builtin_amdgcn_mfma_f32_16x16x32_bf16(pf0, vf0, o_acc[dt], 0, 0, 0);
      o_acc[dt] = __builtin_amdgcn_mfma_f32_16x16x32_bf16(pf1, vf1, o_acc[dt], 0, 0, 0);
    }
  }

  // ---- normalize & store: o_acc row=i=q4*4+r (in strip), col=d=dt*16+l15
  floatx4 inv;
#pragma unroll
  for (int r = 0; r < 4; ++r) inv[r] = 1.0f / lsum[r];
#pragma unroll
  for (int dt = 0; dt < 4; ++dt)
#pragma unroll
    for (int r = 0; r < 4; ++r) {
      int i = i0 + w * 16 + q4 * 4 + r;
      AO[((size_t)(b * 2048 + i)) * 1024 + h * 64 + dt * 16 + l15] =
          (bf16_t)(o_acc[dt][r] * inv[r]);
    }
}

// ---------------- launch ----------------
extern "C" void kernel_launch(void* const* d_in, const int* in_sizes, int n_in,
                              void* d_out, int out_size, void* d_ws, size_t ws_size,
                              hipStream_t stream) {
  const float* x  = (const float*)d_in[0];
  const float* Wq = (const float*)d_in[1];
  const float* bq = (const float*)d_in[2];
  const float* Wk = (const float*)d_in[3];
  const float* bk = (const float*)d_in[4];
  const float* Wv = (const float*)d_in[5];
  const float* bv = (const float*)d_in[6];
  const float* Wo = (const float*)d_in[7];
  const float* bo = (const float*)d_in[8];

  char* ws = (char*)d_ws;                      // needs >= 48 MB
  bf16_t* xb  = (bf16_t*)(ws);                 //  8 MB
  bf16_t* wqb = (bf16_t*)(ws + (8u  << 20));   //  2 MB (wq..wo contiguous)
  bf16_t* wkb = (bf16_t*)(ws + (10u << 20));
  bf16_t* wvb = (bf16_t*)(ws + (12u << 20));
  bf16_t* wob = (bf16_t*)(ws + (14u << 20));
  bf16_t* Qb  = (bf16_t*)(ws + (16u << 20));   //  8 MB  [b,t,h,d]
  bf16_t* Kb  = (bf16_t*)(ws + (24u << 20));   //  8 MB  [b,t,h,d]
  bf16_t* Vtb = (bf16_t*)(ws + (32u << 20));   //  8 MB  [b,h*d,t]
  bf16_t* AOb = (bf16_t*)(ws + (40u << 20));   //  8 MB  [b,t,h,d]

  castall<<<8192, 256, 0, stream>>>(x, Wq, Wk, Wv, Wo, xb, wqb);

  // QKV: grid.x = 3*8 n-blocks, grid.y = 32 m-blocks -> 768 blocks = 3/CU exactly
  gemm_qkv<<<dim3(24, 32), 256, 0, stream>>>(
      xb, wqb, wkb, wvb, bq, bk, bv, Qb, Kb, Vtb);

  attn_kernel<<<1024, 256, 0, stream>>>(Qb, Kb, Vtb, AOb);

  // out: 64x128 tiles -> grid (8, 64) = 512 blocks = 2/CU exactly
  gemm_out<<<dim3(8, 64), 256, 0, stream>>>(AOb, wob, bo, (float*)d_out);
}